// Round 9
// baseline (403.949 us; speedup 1.0000x reference)
//
#include <hip/hip_runtime.h>
#include <math.h>

#define D_DIM 1024
#define S_DIM 4096
#define B_DIM 4
#define CHUNK 64
#define NC (S_DIM / CHUNK)
#define M_DIM (B_DIM * S_DIM)   // 16384 rows
#define MD ((size_t)M_DIM * D_DIM)

typedef __bf16 bf16_t;
typedef __attribute__((ext_vector_type(8))) __bf16 bf16x8;
typedef __attribute__((ext_vector_type(4))) __bf16 bf16x4;
typedef __attribute__((ext_vector_type(2))) __bf16 bf16x2;
typedef __attribute__((ext_vector_type(4))) float f32x4;

// ---------------------------------------------------------------------------
// async 16B/lane global->LDS. LDS dest is wave-uniform base + lane*16.
// ---------------------------------------------------------------------------
__device__ __forceinline__ void async_copy16(const void* g, void* lds) {
  __builtin_amdgcn_global_load_lds(
      (const __attribute__((address_space(1))) unsigned int*)g,
      (__attribute__((address_space(3))) unsigned int*)lds, 16, 0, 0);
}

#define SB __builtin_amdgcn_s_barrier()
#define PRIO1 __builtin_amdgcn_s_setprio(1)
#define PRIO0 __builtin_amdgcn_s_setprio(0)

// ---------------------------------------------------------------------------
// 256x256-tile 8-phase GEMM. R8 base with ONE change: each phase's ds_reads
// are issued AFTER the phase's first barrier (inside the MFMA window), B
// fragments first. Previously reads sat in the inter-barrier window, fully
// serializing LDS issue/drain with the MFMA window (34% MfmaUtil @ 1556
// cyc/phase vs 621 cyc of MFMA). In-window reads let the compiler's
// fine-grained lgkmcnt(N) hide read drain under MFMA issue.
// WAR safety: a wave's reads complete before its last MFMA of the phase
// (lgkm waits), hence before it passes the phase-end barrier; restaging of
// any region is issued >=1 barrier after that. RAW/vmcnt ledger unchanged:
// vmcnt(4) at phases 4/8 (retires the buffer about to be read), vmcnt(0)
// on the last iteration.
// MODE 0 (MEGA): bf16 out [t][16384][1024]; MODE 2 (FINAL): f32 out + res.
// ---------------------------------------------------------------------------
template <int MODE>
__global__ __launch_bounds__(512, 2) void gemm256(const bf16_t* __restrict__ A,
                                                  const bf16_t* __restrict__ Bt,
                                                  const float* __restrict__ bias,
                                                  const float* __restrict__ res,
                                                  float* __restrict__ Cf,
                                                  bf16_t* __restrict__ Cb) {
  constexpr int K = D_DIM;
  constexpr int NB_N = (MODE == 0) ? 12 : 4;   // N/256
  __shared__ bf16_t sm[65536];                  // 128 KiB: buf0 | buf1

  const int bid = blockIdx.x;
  const int xcd = bid & 7;
  const int slot = bid >> 3;
  const int bm = (xcd * 8 + slot / NB_N) * 256;  // 64 M-tiles, 8 per XCD
  const int bn = (slot % NB_N) * 256;

  const int tid = threadIdx.x;
  const int lane = tid & 63;
  const int wave = tid >> 6;
  const int wm = wave >> 2;        // 0..1  (128-row half)
  const int wn = wave & 3;         // 0..3  (64-col quarter)
  const int quad = lane >> 4;
  const int l15 = lane & 15;
  const int lane8 = lane * 8;      // element offset of this lane's 16B chunk
  const int bg = (wn & 1) * 4;     // wave's B group base within its half

  // ---- per-thread permuted global source (chunk c = s*512 + tid) ----
  const int c0 = tid, c1 = tid + 512;
#define ROWOF(c) ((((c) >> 7) & 7) * 16 + ((c) & 15))
#define KGOF(c) ((((c) >> 6) & 1) * 4 + (((c) >> 4) & 3))
  const bf16_t* gA0 = A + (size_t)(bm + ROWOF(c0)) * K + KGOF(c0) * 8;
  const bf16_t* gA1 = A + (size_t)(bm + ROWOF(c1)) * K + KGOF(c1) * 8;
  const bf16_t* gB0 = Bt + (size_t)(bn + ROWOF(c0)) * K + KGOF(c0) * 8;
  const bf16_t* gB1 = Bt + (size_t)(bn + ROWOF(c1)) * K + KGOF(c1) * 8;

  // ---- LDS bases ----
  bf16_t* stA0 = sm + wave * 512;
  bf16_t* stB0 = sm + 16384 + wave * 512;
  bf16_t* stA1 = sm + 32768 + wave * 512;
  bf16_t* stB1 = sm + 49152 + wave * 512;
  const bf16_t* A0p = sm + wm * 8192 + lane8;
  const bf16_t* B0p = sm + 16384 + (wn >> 1) * 8192 + lane8;
  const bf16_t* A1p = sm + 32768 + wm * 8192 + lane8;
  const bf16_t* B1p = sm + 49152 + (wn >> 1) * 8192 + lane8;

#define STG(gp0, gp1, kofs, db, hx)                                        \
  do {                                                                     \
    async_copy16(gp0 + (size_t)(hx)*131072 + (kofs), (db) + (hx)*8192);    \
    async_copy16(gp1 + (size_t)(hx)*131072 + (kofs), (db) + (hx)*8192 + 4096); \
  } while (0)

  f32x4 acc[8][4];
#pragma unroll
  for (int i = 0; i < 8; i++)
#pragma unroll
    for (int j = 0; j < 4; j++) acc[i][j] = (f32x4){0.f, 0.f, 0.f, 0.f};

  bf16x8 af[4][2], bl[2][2], bh[2][2];

#define RDA(P, MS)                                                         \
  _Pragma("unroll") for (int m = 0; m < 4; ++m) {                          \
    af[m][0] = *(const bf16x8*)((P) + (((MS) + m) * 2 + 0) * 512);         \
    af[m][1] = *(const bf16x8*)((P) + (((MS) + m) * 2 + 1) * 512);         \
  }
#define RDB(P, DST, NS)                                                    \
  _Pragma("unroll") for (int n = 0; n < 2; ++n) {                          \
    DST[n][0] = *(const bf16x8*)((P) + (((NS) + n) * 2 + 0) * 512);        \
    DST[n][1] = *(const bf16x8*)((P) + (((NS) + n) * 2 + 1) * 512);        \
  }
#define MFQ(MB, NB, BB)                                                    \
  do {                                                                     \
    PRIO1;                                                                 \
    _Pragma("unroll") for (int m = 0; m < 4; ++m)                          \
        _Pragma("unroll") for (int n = 0; n < 2; ++n) {                    \
      acc[(MB) + m][(NB) + n] = __builtin_amdgcn_mfma_f32_16x16x32_bf16(   \
          af[m][0], BB[n][0], acc[(MB) + m][(NB) + n], 0, 0, 0);           \
      acc[(MB) + m][(NB) + n] = __builtin_amdgcn_mfma_f32_16x16x32_bf16(   \
          af[m][1], BB[n][1], acc[(MB) + m][(NB) + n], 0, 0, 0);           \
    }                                                                      \
    PRIO0;                                                                 \
  } while (0)

  // ---- prologue: stage buf0 (t=0, B then A) + buf1 B-halves (t=1) ----
  STG(gB0, gB1, 0, stB0, 0);
  STG(gB0, gB1, 0, stB0, 1);
  STG(gA0, gA1, 0, stA0, 0);
  STG(gA0, gA1, 0, stA0, 1);
  STG(gB0, gB1, 64, stB1, 0);
  STG(gB0, gB1, 64, stB1, 1);
  asm volatile("s_waitcnt vmcnt(4)" ::: "memory");  // buf0's 8 loads done
  SB;

  for (int i = 0; i < 8; ++i) {
    const size_t kA1 = (size_t)(2 * i + 1) * 64;
    const size_t kN = (size_t)(2 * i + 2) * 64;
    const bool pf = (i < 7);

    // ph1: stage buf1.A h0 (t=2i+1); [reads in MFMA window] bl,afL; Q(0,0)
    STG(gA0, gA1, kA1, stA1, 0);
    SB;
    RDB(B0p, bl, bg);
    RDA(A0p, 0);
    MFQ(0, 0, bl);
    SB;

    // ph2: stage buf1.A h1; rd bh; Q(0,1)
    STG(gA0, gA1, kA1, stA1, 1);
    SB;
    RDB(B0p, bh, bg + 2);
    MFQ(0, 2, bh);
    SB;

    // ph3: stage buf0.B h0 (t=2i+2); rd afH; Q(1,1)
    if (pf) STG(gB0, gB1, kN, stB0, 0);
    SB;
    RDA(A0p, 4);
    MFQ(4, 2, bh);
    SB;

    // ph4: stage buf0.B h1; Q(1,0); vmcnt checkpoint -> buf1 ready
    if (pf) STG(gB0, gB1, kN, stB0, 1);
    SB;
    MFQ(4, 0, bl);
    if (pf) { asm volatile("s_waitcnt vmcnt(4)" ::: "memory"); }
    else    { asm volatile("s_waitcnt vmcnt(0)" ::: "memory"); }
    SB;

    // ph5: stage buf0.A h0 (t=2i+2); rd bl,afL (buf1); Q(0,0)
    if (pf) STG(gA0, gA1, kN, stA0, 0);
    SB;
    RDB(B1p, bl, bg);
    RDA(A1p, 0);
    MFQ(0, 0, bl);
    SB;

    // ph6: stage buf0.A h1; rd bh; Q(0,1)
    if (pf) STG(gA0, gA1, kN, stA0, 1);
    SB;
    RDB(B1p, bh, bg + 2);
    MFQ(0, 2, bh);
    SB;

    // ph7: stage buf1.B h0 (t=2i+3); rd afH; Q(1,1)
    if (pf) STG(gB0, gB1, kN + 64, stB1, 0);
    SB;
    RDA(A1p, 4);
    MFQ(4, 2, bh);
    SB;

    // ph8: stage buf1.B h1; Q(1,0); vmcnt checkpoint -> buf0(t+2) ready
    if (pf) STG(gB0, gB1, kN + 64, stB1, 1);
    SB;
    MFQ(4, 0, bl);
    if (pf) { asm volatile("s_waitcnt vmcnt(4)" ::: "memory"); }
    else    { asm volatile("s_waitcnt vmcnt(0)" ::: "memory"); }
    SB;
  }
  __builtin_amdgcn_sched_barrier(0);

  // ---- epilogue: C/D layout col=lane&15, row=quad*4+reg ----
  // mf-outer / nf-inner: each 128B output line completes in 4 consecutive
  // stores -> full-line write combining (verified: WRITE_SIZE = 96 MiB).
  const int baserow = bm + wm * 128;
  const int basecol = bn + wn * 64 + l15;
  float bvv[4];
#pragma unroll
  for (int nf = 0; nf < 4; ++nf) bvv[nf] = bias[basecol + nf * 16];
#pragma unroll
  for (int mf = 0; mf < 8; ++mf) {
#pragma unroll
    for (int r = 0; r < 4; ++r) {
      const int m = baserow + mf * 16 + quad * 4 + r;
#pragma unroll
      for (int nf = 0; nf < 4; ++nf) {
        const int n = basecol + nf * 16;
        float v = acc[mf][nf][r] + bvv[nf];
        if (MODE == 2) {
          v += res[(size_t)m * D_DIM + n];
          Cf[(size_t)m * D_DIM + n] = v;
        } else {
          Cb[(size_t)(n >> 10) * MD + (size_t)m * D_DIM + (n & 1023)] =
              (bf16_t)v;
        }
      }
    }
  }
#undef ROWOF
#undef KGOF
#undef STG
#undef RDA
#undef RDB
#undef MFQ
}

// ---------------------------------------------------------------------------
// legacy 128x128 bf16 MFMA GEMM — used only for MODE 3 (WFUSE):
// A=WkpT||WqpT [2048,1024]; tsel=bm>>10 selects Bt half and out half;
// out bf16 [2][1024][1024], no bias.
// ---------------------------------------------------------------------------
template <int MODE>
__global__ __launch_bounds__(256) void gemm_mfma(const bf16_t* __restrict__ A,
                                                 const bf16_t* __restrict__ Bt,
                                                 const float* __restrict__ bias,
                                                 const float* __restrict__ res,
                                                 float* __restrict__ Cf,
                                                 bf16_t* __restrict__ Cb) {
  constexpr int K = D_DIM;
  constexpr int NB_N = (MODE == 0) ? 24 : 8;
  constexpr int NB_M = (MODE == 3) ? 16 : 128;
  __shared__ bf16_t sm[4 * 4096];   // As0 | As1 | Bs0 | Bs1, each 128x32

  const int bid = blockIdx.x;
  const int xcd = bid & 7;
  const int slot = bid >> 3;
  const int bm = (xcd * (NB_M / 8) + slot / NB_N) * 128;
  const int bn = (slot % NB_N) * 128;

  const int tid = threadIdx.x;
  const int lane = tid & 63;
  const int wave = tid >> 6;
  const int wm = wave & 1, wn = wave >> 1;
  const int quad = lane >> 4;
  const int l15 = lane & 15;

  bf16_t* As0 = sm;
  bf16_t* As1 = sm + 4096;
  bf16_t* Bs0 = sm + 8192;
  bf16_t* Bs1 = sm + 12288;

  const bf16_t* BtP = Bt;
  if (MODE == 3) BtP = Bt + (size_t)(bm >> 10) * D_DIM * D_DIM;

  f32x4 acc[4][4];
#pragma unroll
  for (int i = 0; i < 4; i++)
#pragma unroll
    for (int j = 0; j < 4; j++) acc[i][j] = (f32x4){0.f, 0.f, 0.f, 0.f};

  const int e0 = tid, e1 = tid + 256;
  const int wofs = wave * 512;
  const bf16_t* a0 = A + (size_t)(bm + (e0 >> 2)) * K + (e0 & 3) * 8;
  const bf16_t* a1 = A + (size_t)(bm + (e1 >> 2)) * K + (e1 & 3) * 8;
  const bf16_t* b0 = BtP + (size_t)(bn + (e0 >> 2)) * K + (e0 & 3) * 8;
  const bf16_t* b1 = BtP + (size_t)(bn + (e1 >> 2)) * K + (e1 & 3) * 8;

  for (int k0 = 0; k0 < K; k0 += 64) {
    async_copy16(a0 + k0, As0 + wofs);
    async_copy16(a1 + k0, As0 + 2048 + wofs);
    async_copy16(b0 + k0, Bs0 + wofs);
    async_copy16(b1 + k0, Bs0 + 2048 + wofs);
    async_copy16(a0 + k0 + 32, As1 + wofs);
    async_copy16(a1 + k0 + 32, As1 + 2048 + wofs);
    async_copy16(b0 + k0 + 32, Bs1 + wofs);
    async_copy16(b1 + k0 + 32, Bs1 + 2048 + wofs);
    __syncthreads();

#pragma unroll
    for (int h = 0; h < 2; h++) {
      const bf16_t* Ah = h ? As1 : As0;
      const bf16_t* Bh = h ? Bs1 : Bs0;
      bf16x8 af[4], bfr[4];
#pragma unroll
      for (int t = 0; t < 4; t++) {
        af[t] = *(const bf16x8*)(Ah + (size_t)(wm * 64 + t * 16 + l15) * 32 + quad * 8);
        bfr[t] = *(const bf16x8*)(Bh + (size_t)(wn * 64 + t * 16 + l15) * 32 + quad * 8);
      }
#pragma unroll
      for (int mt = 0; mt < 4; mt++)
#pragma unroll
        for (int nt = 0; nt < 4; nt++)
          acc[mt][nt] =
              __builtin_amdgcn_mfma_f32_16x16x32_bf16(af[mt], bfr[nt], acc[mt][nt], 0, 0, 0);
    }
    __syncthreads();
  }

  const int baserow = bm + wm * 64;
  const int basecol = bn + wn * 64 + l15;
#pragma unroll
  for (int mt = 0; mt < 4; mt++) {
#pragma unroll
    for (int nt = 0; nt < 4; nt++) {
      const int n = basecol + nt * 16;
      const float bv = (MODE == 3) ? 0.f : bias[n];
#pragma unroll
      for (int r = 0; r < 4; r++) {
        const int m = baserow + mt * 16 + quad * 4 + r;
        float v = acc[mt][nt][r] + bv;
        if (MODE == 2) {
          v += res[(size_t)m * D_DIM + n];
          Cf[(size_t)m * D_DIM + n] = v;
        } else if (MODE == 0) {
          Cb[(size_t)(bn >> 10) * MD + (size_t)m * D_DIM + (n & 1023)] = (bf16_t)v;
        } else {  // MODE 3
          Cb[(size_t)(bm >> 10) * D_DIM * D_DIM + (size_t)(m & 1023) * D_DIM + n] =
              (bf16_t)v;
        }
      }
    }
  }
}

// ---------------------------------------------------------------------------
// Prelude: z<4  -> weight transpose+cast (Wt[n][k] = (bf16)W[k][n]);
//          z in [4,22) -> flat fp32->bf16 cast of x | Wk | Wq;
//          z==22 -> fused bias (K-split GEMV), folded in to save a dispatch.
// ---------------------------------------------------------------------------
__global__ __launch_bounds__(256) void prep_all(
    const float* __restrict__ s0, const float* __restrict__ s1,
    const float* __restrict__ s2, const float* __restrict__ s3,
    bf16_t* __restrict__ d0, bf16_t* __restrict__ d1,
    bf16_t* __restrict__ d2, bf16_t* __restrict__ d3,
    const float* __restrict__ x, const float* __restrict__ Wk,
    const float* __restrict__ Wq, bf16_t* __restrict__ xb,
    bf16_t* __restrict__ wkb, bf16_t* __restrict__ wqb,
    const float* __restrict__ bv, const float* __restrict__ bk,
    const float* __restrict__ bkp, const float* __restrict__ bq,
    const float* __restrict__ bqp, float* __restrict__ fb) {
  const int z = blockIdx.z;
  if (z == 22) {
    // fused bias: fb[c]=bv[c]; fb[1024+c]=bk@Wkp[:,c]+bkp[c]; fb[2048+c] q.
    // grid slice: x<16 (column tiles of 64), y<3 (t). 4 K-partitions x 64 cols.
    if (blockIdx.x >= 16 || blockIdx.y >= 3) return;
    const int t = blockIdx.y;
    const int cb = blockIdx.x * 64;
    const int c = threadIdx.x & 63;
    const int p = threadIdx.x >> 6;
    if (t == 0) {
      if (p == 0) fb[cb + c] = bv[cb + c];
      return;
    }
    const float* W = (t == 1) ? s1 : s2;   // Wkp : Wqp (fp32 originals)
    const float* b1 = (t == 1) ? bk : bq;
    const float* b2 = (t == 1) ? bkp : bqp;
    const int k0 = p * 256;
    float s = 0.f;
#pragma unroll 8
    for (int k = 0; k < 256; k++)
      s = fmaf(b1[k0 + k], W[(size_t)(k0 + k) * D_DIM + cb + c], s);
    __shared__ float red[4][64];
    red[p][c] = s;
    __syncthreads();
    if (p == 0)
      fb[t * 1024 + cb + c] =
          red[0][c] + red[1][c] + red[2][c] + red[3][c] + b2[cb + c];
  } else if (z < 4) {
    const float* srcs[4] = {s0, s1, s2, s3};
    bf16_t* dsts[4] = {d0, d1, d2, d3};
    const float* W = srcs[z];
    bf16_t* Wt = dsts[z];
    __shared__ float tile[32][33];
    const int bx = blockIdx.x * 32;  // n
    const int by = blockIdx.y * 32;  // k
    const int tx = threadIdx.x & 31, ty = threadIdx.x >> 5;  // 32 x 8
#pragma unroll
    for (int r = 0; r < 32; r += 8)
      tile[ty + r][tx] = W[(size_t)(by + ty + r) * D_DIM + bx + tx];
    __syncthreads();
#pragma unroll
    for (int r = 0; r < 32; r += 8)
      Wt[(size_t)(bx + ty + r) * D_DIM + by + tx] = (bf16_t)tile[tx][ty + r];
  } else {
    // 18 z-slices x 1024 blocks x 256 thr = 4718592 float4 groups exactly
    size_t i = ((size_t)(z - 4) * 1024 + blockIdx.y * 32 + blockIdx.x) * 256 +
               threadIdx.x;
    const float* src;
    bf16_t* dst;
    size_t off;
    if (i < 4194304) { src = x; dst = xb; off = i; }
    else if (i < 4456448) { src = Wk; dst = wkb; off = i - 4194304; }
    else { src = Wq; dst = wqb; off = i - 4456448; }
    const float4 v = ((const float4*)src)[off];
    bf16x4 o;
    o[0] = (bf16_t)v.x; o[1] = (bf16_t)v.y; o[2] = (bf16_t)v.z; o[3] = (bf16_t)v.w;
    ((bf16x4*)dst)[off] = o;
  }
}

// ---------------------------------------------------------------------------
// Fused phasor scan + LayerNorm. Block = (chunk, b), 512 threads, 64 KB LDS.
// Trig via native __sincosf (phases O(1); error ~1e-6 << bf16 rounding).
// Tail: block (0,0) also reduces the 128 ortho partials (ready by stream
// order) -> saves the ortho_final dispatch.
// ---------------------------------------------------------------------------
__global__ __launch_bounds__(512) void scan_ln(const bf16_t* __restrict__ vb,
                                               const bf16_t* __restrict__ kp,
                                               const bf16_t* __restrict__ qp,
                                               const float* __restrict__ g,
                                               const float* __restrict__ bl,
                                               bf16_t* __restrict__ outb,
                                               const float* __restrict__ partial,
                                               float* __restrict__ orthop) {
  __shared__ bf16_t retl[32 * 1024];   // 64 KB
  __shared__ float osum[8];
  const int chunk = blockIdx.x;
  const int b = blockIdx.y;
  const int tid = threadIdx.x;
  const int lane = tid & 63, wave = tid >> 6;
  const int c = tid * 2;
  const size_t base = ((size_t)(b * S_DIM + chunk * CHUNK)) * D_DIM + c;
  float2 mr = {0.f, 0.f}, mi = {0.f, 0.f};
  const float inv = 0.015625f;  // 1/sqrt(4096)

  for (int half = 0; half < 2; half++) {
#pragma unroll 4
    for (int s8 = 0; s8 < 32; s8++) {
      const int s = half * 32 + s8;
      const size_t off = base + (size_t)s * D_DIM;
      bf16x2 v2 = *(const bf16x2*)(vb + off);
      bf16x2 k2 = *(const bf16x2*)(kp + off);
      bf16x2 q2 = *(const bf16x2*)(qp + off);
      float sk, ck, sq, cq;
      __sincosf((float)k2[0], &sk, &ck);
      mr.x = fmaf((float)v2[0], ck, mr.x);
      mi.x = fmaf((float)v2[0], sk, mi.x);
      __sincosf((float)k2[1], &sk, &ck);
      mr.y = fmaf((float)v2[1], ck, mr.y);
      mi.y = fmaf((float)v2[1], sk, mi.y);
      bf16x2 r;
      __sincosf((float)q2[0], &sq, &cq);
      r[0] = (bf16_t)((mr.x * cq + mi.x * sq) * inv);
      __sincosf((float)q2[1], &sq, &cq);
      r[1] = (bf16_t)((mr.y * cq + mi.y * sq) * inv);
      *(bf16x2*)(retl + s8 * 1024 + c) = r;
    }
    __syncthreads();
#pragma unroll
    for (int j = 0; j < 4; j++) {
      const int r8 = wave * 4 + j;
      const int col0 = lane * 16;
      const bf16x8 va = *(const bf16x8*)(retl + r8 * 1024 + col0);
      const bf16x8 vb8 = *(const bf16x8*)(retl + r8 * 1024 + col0 + 8);
      float vf[16];
#pragma unroll
      for (int k = 0; k < 8; k++) { vf[k] = (float)va[k]; vf[8 + k] = (float)vb8[k]; }
      float s = 0.f, ss = 0.f;
#pragma unroll
      for (int k = 0; k < 16; k++) { s += vf[k]; ss += vf[k] * vf[k]; }
#pragma unroll
      for (int o = 32; o > 0; o >>= 1) {
        s += __shfl_down(s, o);
        ss += __shfl_down(ss, o);
      }
      s = __shfl(s, 0);
      ss = __shfl(ss, 0);
      const float mu = s * (1.f / D_DIM);
      const float var = ss * (1.f / D_DIM) - mu * mu;
      const float rs = 1.f / sqrtf(var + 1e-5f);
      const int m = b * S_DIM + chunk * CHUNK + half * 32 + r8;
      bf16x8 o1, o2;
#pragma unroll
      for (int q = 0; q < 4; q++) {
        const float4 gv = *(const float4*)(g + col0 + 4 * q);
        const float4 bv = *(const float4*)(bl + col0 + 4 * q);
        const int kbase = 4 * q;
        float r0 = (vf[kbase + 0] - mu) * rs * gv.x + bv.x;
        float r1 = (vf[kbase + 1] - mu) * rs * gv.y + bv.y;
        float r2 = (vf[kbase + 2] - mu) * rs * gv.z + bv.z;
        float r3 = (vf[kbase + 3] - mu) * rs * gv.w + bv.w;
        if (q < 2) {
          o1[kbase + 0] = (bf16_t)r0; o1[kbase + 1] = (bf16_t)r1;
          o1[kbase + 2] = (bf16_t)r2; o1[kbase + 3] = (bf16_t)r3;
        } else {
          o2[kbase - 8] = (bf16_t)r0; o2[kbase - 7] = (bf16_t)r1;
          o2[kbase - 6] = (bf16_t)r2; o2[kbase - 5] = (bf16_t)r3;
        }
      }
      *(bf16x8*)(outb + (size_t)m * D_DIM + col0) = o1;
      *(bf16x8*)(outb + (size_t)m * D_DIM + col0 + 8) = o2;
    }
    __syncthreads();
  }

  // ---- ortho finalize (block (0,0) only; partial[] ready by stream order) --
  if (blockIdx.x == 0 && blockIdx.y == 0) {
    float s = (tid < 128) ? partial[tid] : 0.f;
#pragma unroll
    for (int o = 32; o > 0; o >>= 1) s += __shfl_down(s, o);
    if (lane == 0) osum[wave] = s;
    __syncthreads();
    if (tid == 0) {
      double tot = (double)osum[0] + osum[1];  // waves 2+ contributed zeros
      const double denom = (double)(32 * 31) * 1024.0 + 1e-6;
      orthop[0] = (float)(tot / denom);
    }
  }
}

// ---------------------------------------------------------------------------
// Ortho loss from bf16 kphase: cos(kp_i)cos(kp_j)+sin..sin.. = cos(kp_i-kp_j)
// ---------------------------------------------------------------------------
__global__ __launch_bounds__(256) void ortho_partial(const bf16_t* __restrict__ kp,
                                                     const int* __restrict__ idx,
                                                     float* __restrict__ partial) {
  const int i = blockIdx.x;  // 0..31
  const int b = blockIdx.y;  // 0..3
  const int ri = idx[i];
  const bf16x4 ab = *(const bf16x4*)(kp + ((size_t)b * S_DIM + ri) * D_DIM + threadIdx.x * 4);
  float a0 = (float)ab[0], a1 = (float)ab[1], a2 = (float)ab[2], a3 = (float)ab[3];
  float sum = 0.f;
  for (int j = 0; j < 32; j++) {
    if (j == i) continue;
    const int rj = idx[j];
    const bf16x4 cb = *(const bf16x4*)(kp + ((size_t)b * S_DIM + rj) * D_DIM + threadIdx.x * 4);
    float d0 = __cosf(a0 - (float)cb[0]);
    float d1 = __cosf(a1 - (float)cb[1]);
    float d2 = __cosf(a2 - (float)cb[2]);
    float d3 = __cosf(a3 - (float)cb[3]);
    sum += d0 * d0 + d1 * d1 + d2 * d2 + d3 * d3;
  }
#pragma unroll
  for (int o = 32; o > 0; o >>= 1) sum += __shfl_down(sum, o);
  __shared__ float red[4];
  if ((threadIdx.x & 63) == 0) red[threadIdx.x >> 6] = sum;
  __syncthreads();
  if (threadIdx.x == 0) partial[b * 32 + i] = red[0] + red[1] + red[2] + red[3];
}

// ---------------------------------------------------------------------------
// Orchestration (6 dispatches). ws layout (MB offsets; peak 160 MB):
//   [  0,  6) QKVT bf16 [3072,1024] = [WvT | WkkpT | WqqpT]
//   [  6,  8) WoT            [  8, 12) WkpT||WqpT [2048,1024]
//   [ 12,  +) fused bias (3072 f32) + partial (128 f32)
//   [ 13, 17) Wk_b||Wq_b (dead after wfuse GEMM)
//   [ 32, 64) xb             -> lnb after mega GEMM
//   [ 64, 96) value_b        [ 96,128) kp_b        [128,160) qp_b
// ---------------------------------------------------------------------------
extern "C" void kernel_launch(void* const* d_in, const int* in_sizes, int n_in,
                              void* d_out, int out_size, void* d_ws, size_t ws_size,
                              hipStream_t stream) {
  const float* x = (const float*)d_in[0];
  const float* Wk = (const float*)d_in[1];
  const float* bk = (const float*)d_in[2];
  const float* Wv = (const float*)d_in[3];
  const float* bv = (const float*)d_in[4];
  const float* Wq = (const float*)d_in[5];
  const float* bq = (const float*)d_in[6];
  const float* Wkp = (const float*)d_in[7];
  const float* bkp = (const float*)d_in[8];
  const float* Wqp = (const float*)d_in[9];
  const float* bqp = (const float*)d_in[10];
  const float* ln_g = (const float*)d_in[11];
  const float* ln_b = (const float*)d_in[12];
  const float* Wo = (const float*)d_in[13];
  const float* bo = (const float*)d_in[14];
  const int* idx = (const int*)d_in[15];

  float* out = (float*)d_out;
  float* ortho_out = out + MD;

  char* ws = (char*)d_ws;
  const size_t MB = 1024 * 1024;
  bf16_t* QKVT = (bf16_t*)(ws + 0 * MB);     // [3072,1024]
  bf16_t* WoT = (bf16_t*)(ws + 6 * MB);
  bf16_t* WkpT2 = (bf16_t*)(ws + 8 * MB);    // [2048,1024]
  float* fbias = (float*)(ws + 12 * MB);     // 3072
  float* partial = (float*)(ws + 12 * MB + 16 * 1024);  // 128
  bf16_t* Wkqb = (bf16_t*)(ws + 13 * MB);    // Wk_b || Wq_b  [2][1024][1024]
  bf16_t* xb = (bf16_t*)(ws + 32 * MB);
  bf16_t* mega_out = (bf16_t*)(ws + 64 * MB);  // [3][16384][1024]
  bf16_t* kp_b = mega_out + MD;
  bf16_t* qp_b = mega_out + 2 * MD;
  bf16_t* lnb = (bf16_t*)(ws + 32 * MB);     // reuses xb (dead after mega)

  // 0. prelude: transposes + casts + fused bias (one dispatch), wfuse GEMM
  prep_all<<<dim3(32, 32, 23), 256, 0, stream>>>(
      Wv, Wkp, Wqp, Wo, QKVT, WkpT2, WkpT2 + (size_t)D_DIM * D_DIM, WoT,
      x, Wk, Wq, xb, Wkqb, Wkqb + (size_t)D_DIM * D_DIM,
      bv, bk, bkp, bq, bqp, fbias);
  // WkkpT/WqqpT = (WkpT||WqpT) @ (Wk_b||Wq_b)^T  -> QKVT rows [1024,3072)
  gemm_mfma<3><<<128, 256, 0, stream>>>(WkpT2, Wkqb, nullptr, nullptr, nullptr,
                                        QKVT + (size_t)D_DIM * D_DIM);

  // 1. mega GEMM (8-phase 256^2): [value|kp|qp] = xb @ QKVT^T + fbias
  gemm256<0><<<768, 512, 0, stream>>>(xb, QKVT, fbias, nullptr, nullptr,
                                      mega_out);
  // 2. ortho from kp_b
  ortho_partial<<<dim3(32, B_DIM), 256, 0, stream>>>(kp_b, idx, partial);
  // 3. fused trig + chunk cumsum + retrieve + LayerNorm -> lnb (xb dead);
  //    block (0,0) also finalizes ortho scalar.
  scan_ln<<<dim3(NC, B_DIM), 512, 0, stream>>>(mega_out, kp_b, qp_b, ln_g, ln_b,
                                               lnb, partial, ortho_out);
  // 4. out = x + lnb@Wo + bo  (8-phase 256^2)
  gemm256<2><<<256, 512, 0, stream>>>(lnb, WoT, bo, x, out, nullptr);
}

// Round 10
// 397.091 us; speedup vs baseline: 1.0173x; 1.0173x over previous
//
#include <hip/hip_runtime.h>
#include <math.h>

#define D_DIM 1024
#define S_DIM 4096
#define B_DIM 4
#define CHUNK 64
#define NC (S_DIM / CHUNK)
#define M_DIM (B_DIM * S_DIM)   // 16384 rows
#define MD ((size_t)M_DIM * D_DIM)

typedef __bf16 bf16_t;
typedef __attribute__((ext_vector_type(8))) __bf16 bf16x8;
typedef __attribute__((ext_vector_type(4))) __bf16 bf16x4;
typedef __attribute__((ext_vector_type(2))) __bf16 bf16x2;
typedef __attribute__((ext_vector_type(4))) float f32x4;

// ---------------------------------------------------------------------------
// async 16B/lane global->LDS. LDS dest is wave-uniform base + lane*16.
// ---------------------------------------------------------------------------
__device__ __forceinline__ void async_copy16(const void* g, void* lds) {
  __builtin_amdgcn_global_load_lds(
      (const __attribute__((address_space(1))) unsigned int*)g,
      (__attribute__((address_space(3))) unsigned int*)lds, 16, 0, 0);
}

#define SB __builtin_amdgcn_s_barrier()
#define PRIO1 __builtin_amdgcn_s_setprio(1)
#define PRIO0 __builtin_amdgcn_s_setprio(0)

// ---------------------------------------------------------------------------
// 256x256-tile GEMM, 4 fused phases/iteration (32 MFMA per phase). R9's
// 8-phase structure spent 16 barrier crossings/iter; per-iter MFMA floor is
// ~4966 cyc/SIMD and LDS-read load ~4608 cyc/CU (different pipes), yet
// measured 12448 cyc/iter -> per-phase fixed cost (barrier skew + read-drain
// ramp) dominates. Fusing quadrant pairs halves barrier count and doubles
// MFMA run length per drain.
//
// Per iteration (buf0 = K-tile 2i, buf1 = 2i+1; ' = next tiles):
//  phA: stg buf1.A h0+h1 | SB | rd bl,bh,afL | Q00,Q01 | SB
//  phB: stg buf0.B' h0+h1| SB | rd afH       | Q11,Q10 | vmcnt(4) | SB
//  phC: stg buf0.A' h0+h1| SB | rd bl,bh,afL (buf1) | Q00,Q01 | SB
//  phD: stg buf1.B' h0+h1| SB | rd afH (buf1)| Q11,Q10 | vmcnt(4) | SB
// FIFO ledger (4 loads/phase): prologue 12 loads, vmcnt(4) -> buf0 ready,
// 4 left (buf1.B). phB's vmcnt(4) retires buf1.B+buf1.A -> buf1 ready;
// phD's retires buf0.B'+buf0.A' -> buf0' ready. Last iteration: vmcnt(0).
// WAR: each restaged region's last reader completed (lgkm before its MFMA)
// before the barrier preceding the stage. Accumulation order unchanged.
// LDS chunk layout + permuted global source as before (conflict-free,
// verified SQ_LDS_BANK_CONFLICT==0).
// MODE 0 (MEGA): bf16 out [t][16384][1024]; MODE 2 (FINAL): f32 out + res.
// ---------------------------------------------------------------------------
template <int MODE>
__global__ __launch_bounds__(512, 2) void gemm256(const bf16_t* __restrict__ A,
                                                  const bf16_t* __restrict__ Bt,
                                                  const float* __restrict__ bias,
                                                  const float* __restrict__ res,
                                                  float* __restrict__ Cf,
                                                  bf16_t* __restrict__ Cb) {
  constexpr int K = D_DIM;
  constexpr int NB_N = (MODE == 0) ? 12 : 4;   // N/256
  __shared__ bf16_t sm[65536];                  // 128 KiB: buf0 | buf1

  const int bid = blockIdx.x;
  const int xcd = bid & 7;
  const int slot = bid >> 3;
  const int bm = (xcd * 8 + slot / NB_N) * 256;  // 64 M-tiles, 8 per XCD
  const int bn = (slot % NB_N) * 256;

  const int tid = threadIdx.x;
  const int lane = tid & 63;
  const int wave = tid >> 6;
  const int wm = wave >> 2;        // 0..1  (128-row half)
  const int wn = wave & 3;         // 0..3  (64-col quarter)
  const int quad = lane >> 4;
  const int l15 = lane & 15;
  const int lane8 = lane * 8;      // element offset of this lane's 16B chunk
  const int bg = (wn & 1) * 4;     // wave's B group base within its half

  // ---- per-thread permuted global source (chunk c = s*512 + tid) ----
  const int c0 = tid, c1 = tid + 512;
#define ROWOF(c) ((((c) >> 7) & 7) * 16 + ((c) & 15))
#define KGOF(c) ((((c) >> 6) & 1) * 4 + (((c) >> 4) & 3))
  const bf16_t* gA0 = A + (size_t)(bm + ROWOF(c0)) * K + KGOF(c0) * 8;
  const bf16_t* gA1 = A + (size_t)(bm + ROWOF(c1)) * K + KGOF(c1) * 8;
  const bf16_t* gB0 = Bt + (size_t)(bn + ROWOF(c0)) * K + KGOF(c0) * 8;
  const bf16_t* gB1 = Bt + (size_t)(bn + ROWOF(c1)) * K + KGOF(c1) * 8;

  // ---- LDS bases ----
  bf16_t* stA0 = sm + wave * 512;
  bf16_t* stB0 = sm + 16384 + wave * 512;
  bf16_t* stA1 = sm + 32768 + wave * 512;
  bf16_t* stB1 = sm + 49152 + wave * 512;
  const bf16_t* A0p = sm + wm * 8192 + lane8;
  const bf16_t* B0p = sm + 16384 + (wn >> 1) * 8192 + lane8;
  const bf16_t* A1p = sm + 32768 + wm * 8192 + lane8;
  const bf16_t* B1p = sm + 49152 + (wn >> 1) * 8192 + lane8;

#define STG(gp0, gp1, kofs, db, hx)                                        \
  do {                                                                     \
    async_copy16(gp0 + (size_t)(hx)*131072 + (kofs), (db) + (hx)*8192);    \
    async_copy16(gp1 + (size_t)(hx)*131072 + (kofs), (db) + (hx)*8192 + 4096); \
  } while (0)

  f32x4 acc[8][4];
#pragma unroll
  for (int i = 0; i < 8; i++)
#pragma unroll
    for (int j = 0; j < 4; j++) acc[i][j] = (f32x4){0.f, 0.f, 0.f, 0.f};

  bf16x8 af[4][2], bl[2][2], bh[2][2];

#define RDA(P, MS)                                                         \
  _Pragma("unroll") for (int m = 0; m < 4; ++m) {                          \
    af[m][0] = *(const bf16x8*)((P) + (((MS) + m) * 2 + 0) * 512);         \
    af[m][1] = *(const bf16x8*)((P) + (((MS) + m) * 2 + 1) * 512);         \
  }
#define RDB(P, DST, NS)                                                    \
  _Pragma("unroll") for (int n = 0; n < 2; ++n) {                          \
    DST[n][0] = *(const bf16x8*)((P) + (((NS) + n) * 2 + 0) * 512);        \
    DST[n][1] = *(const bf16x8*)((P) + (((NS) + n) * 2 + 1) * 512);        \
  }
#define MFQ(MB, NB, BB)                                                    \
  do {                                                                     \
    PRIO1;                                                                 \
    _Pragma("unroll") for (int m = 0; m < 4; ++m)                          \
        _Pragma("unroll") for (int n = 0; n < 2; ++n) {                    \
      acc[(MB) + m][(NB) + n] = __builtin_amdgcn_mfma_f32_16x16x32_bf16(   \
          af[m][0], BB[n][0], acc[(MB) + m][(NB) + n], 0, 0, 0);           \
      acc[(MB) + m][(NB) + n] = __builtin_amdgcn_mfma_f32_16x16x32_bf16(   \
          af[m][1], BB[n][1], acc[(MB) + m][(NB) + n], 0, 0, 0);           \
    }                                                                      \
    PRIO0;                                                                 \
  } while (0)

  // ---- prologue: stage buf0 (B,A) + buf1 B-halves = 12 loads ----
  STG(gB0, gB1, 0, stB0, 0);
  STG(gB0, gB1, 0, stB0, 1);
  STG(gA0, gA1, 0, stA0, 0);
  STG(gA0, gA1, 0, stA0, 1);
  STG(gB0, gB1, 64, stB1, 0);
  STG(gB0, gB1, 64, stB1, 1);
  asm volatile("s_waitcnt vmcnt(4)" ::: "memory");  // buf0's 8 loads done
  SB;

  for (int i = 0; i < 8; ++i) {
    const size_t kA1 = (size_t)(2 * i + 1) * 64;
    const size_t kN = (size_t)(2 * i + 2) * 64;
    const bool pf = (i < 7);

    // phA (buf0): stage buf1.A h0+h1 (t=2i+1); rd bl,bh,afL; Q00+Q01
    STG(gA0, gA1, kA1, stA1, 0);
    STG(gA0, gA1, kA1, stA1, 1);
    SB;
    RDB(B0p, bl, bg);
    RDB(B0p, bh, bg + 2);
    RDA(A0p, 0);
    MFQ(0, 0, bl);
    MFQ(0, 2, bh);
    SB;

    // phB (buf0): stage buf0.B' h0+h1 (t=2i+2); rd afH; Q11+Q10; vmcnt
    if (pf) { STG(gB0, gB1, kN, stB0, 0); STG(gB0, gB1, kN, stB0, 1); }
    SB;
    RDA(A0p, 4);
    MFQ(4, 2, bh);
    MFQ(4, 0, bl);
    if (pf) { asm volatile("s_waitcnt vmcnt(4)" ::: "memory"); }
    else    { asm volatile("s_waitcnt vmcnt(0)" ::: "memory"); }
    SB;

    // phC (buf1): stage buf0.A' h0+h1; rd bl,bh,afL; Q00+Q01
    if (pf) { STG(gA0, gA1, kN, stA0, 0); STG(gA0, gA1, kN, stA0, 1); }
    SB;
    RDB(B1p, bl, bg);
    RDB(B1p, bh, bg + 2);
    RDA(A1p, 0);
    MFQ(0, 0, bl);
    MFQ(0, 2, bh);
    SB;

    // phD (buf1): stage buf1.B' h0+h1 (t=2i+3); rd afH; Q11+Q10; vmcnt
    if (pf) { STG(gB0, gB1, kN + 64, stB1, 0); STG(gB0, gB1, kN + 64, stB1, 1); }
    SB;
    RDA(A1p, 4);
    MFQ(4, 2, bh);
    MFQ(4, 0, bl);
    if (pf) { asm volatile("s_waitcnt vmcnt(4)" ::: "memory"); }
    else    { asm volatile("s_waitcnt vmcnt(0)" ::: "memory"); }
    SB;
  }
  __builtin_amdgcn_sched_barrier(0);

  // ---- epilogue: C/D layout col=lane&15, row=quad*4+reg ----
  // mf-outer / nf-inner: each 128B output line completes in 4 consecutive
  // stores -> full-line write combining (verified: WRITE_SIZE = 96 MiB).
  const int baserow = bm + wm * 128;
  const int basecol = bn + wn * 64 + l15;
  float bvv[4];
#pragma unroll
  for (int nf = 0; nf < 4; ++nf) bvv[nf] = bias[basecol + nf * 16];
#pragma unroll
  for (int mf = 0; mf < 8; ++mf) {
#pragma unroll
    for (int r = 0; r < 4; ++r) {
      const int m = baserow + mf * 16 + quad * 4 + r;
#pragma unroll
      for (int nf = 0; nf < 4; ++nf) {
        const int n = basecol + nf * 16;
        float v = acc[mf][nf][r] + bvv[nf];
        if (MODE == 2) {
          v += res[(size_t)m * D_DIM + n];
          Cf[(size_t)m * D_DIM + n] = v;
        } else {
          Cb[(size_t)(n >> 10) * MD + (size_t)m * D_DIM + (n & 1023)] =
              (bf16_t)v;
        }
      }
    }
  }
#undef ROWOF
#undef KGOF
#undef STG
#undef RDA
#undef RDB
#undef MFQ
}

// ---------------------------------------------------------------------------
// legacy 128x128 bf16 MFMA GEMM — used only for MODE 3 (WFUSE):
// A=WkpT||WqpT [2048,1024]; tsel=bm>>10 selects Bt half and out half;
// out bf16 [2][1024][1024], no bias.
// ---------------------------------------------------------------------------
template <int MODE>
__global__ __launch_bounds__(256) void gemm_mfma(const bf16_t* __restrict__ A,
                                                 const bf16_t* __restrict__ Bt,
                                                 const float* __restrict__ bias,
                                                 const float* __restrict__ res,
                                                 float* __restrict__ Cf,
                                                 bf16_t* __restrict__ Cb) {
  constexpr int K = D_DIM;
  constexpr int NB_N = (MODE == 0) ? 24 : 8;
  constexpr int NB_M = (MODE == 3) ? 16 : 128;
  __shared__ bf16_t sm[4 * 4096];   // As0 | As1 | Bs0 | Bs1, each 128x32

  const int bid = blockIdx.x;
  const int xcd = bid & 7;
  const int slot = bid >> 3;
  const int bm = (xcd * (NB_M / 8) + slot / NB_N) * 128;
  const int bn = (slot % NB_N) * 128;

  const int tid = threadIdx.x;
  const int lane = tid & 63;
  const int wave = tid >> 6;
  const int wm = wave & 1, wn = wave >> 1;
  const int quad = lane >> 4;
  const int l15 = lane & 15;

  bf16_t* As0 = sm;
  bf16_t* As1 = sm + 4096;
  bf16_t* Bs0 = sm + 8192;
  bf16_t* Bs1 = sm + 12288;

  const bf16_t* BtP = Bt;
  if (MODE == 3) BtP = Bt + (size_t)(bm >> 10) * D_DIM * D_DIM;

  f32x4 acc[4][4];
#pragma unroll
  for (int i = 0; i < 4; i++)
#pragma unroll
    for (int j = 0; j < 4; j++) acc[i][j] = (f32x4){0.f, 0.f, 0.f, 0.f};

  const int e0 = tid, e1 = tid + 256;
  const int wofs = wave * 512;
  const bf16_t* a0 = A + (size_t)(bm + (e0 >> 2)) * K + (e0 & 3) * 8;
  const bf16_t* a1 = A + (size_t)(bm + (e1 >> 2)) * K + (e1 & 3) * 8;
  const bf16_t* b0 = BtP + (size_t)(bn + (e0 >> 2)) * K + (e0 & 3) * 8;
  const bf16_t* b1 = BtP + (size_t)(bn + (e1 >> 2)) * K + (e1 & 3) * 8;

  for (int k0 = 0; k0 < K; k0 += 64) {
    async_copy16(a0 + k0, As0 + wofs);
    async_copy16(a1 + k0, As0 + 2048 + wofs);
    async_copy16(b0 + k0, Bs0 + wofs);
    async_copy16(b1 + k0, Bs0 + 2048 + wofs);
    async_copy16(a0 + k0 + 32, As1 + wofs);
    async_copy16(a1 + k0 + 32, As1 + 2048 + wofs);
    async_copy16(b0 + k0 + 32, Bs1 + wofs);
    async_copy16(b1 + k0 + 32, Bs1 + 2048 + wofs);
    __syncthreads();

#pragma unroll
    for (int h = 0; h < 2; h++) {
      const bf16_t* Ah = h ? As1 : As0;
      const bf16_t* Bh = h ? Bs1 : Bs0;
      bf16x8 af[4], bfr[4];
#pragma unroll
      for (int t = 0; t < 4; t++) {
        af[t] = *(const bf16x8*)(Ah + (size_t)(wm * 64 + t * 16 + l15) * 32 + quad * 8);
        bfr[t] = *(const bf16x8*)(Bh + (size_t)(wn * 64 + t * 16 + l15) * 32 + quad * 8);
      }
#pragma unroll
      for (int mt = 0; mt < 4; mt++)
#pragma unroll
        for (int nt = 0; nt < 4; nt++)
          acc[mt][nt] =
              __builtin_amdgcn_mfma_f32_16x16x32_bf16(af[mt], bfr[nt], acc[mt][nt], 0, 0, 0);
    }
    __syncthreads();
  }

  const int baserow = bm + wm * 64;
  const int basecol = bn + wn * 64 + l15;
#pragma unroll
  for (int mt = 0; mt < 4; mt++) {
#pragma unroll
    for (int nt = 0; nt < 4; nt++) {
      const int n = basecol + nt * 16;
      const float bv = (MODE == 3) ? 0.f : bias[n];
#pragma unroll
      for (int r = 0; r < 4; r++) {
        const int m = baserow + mt * 16 + quad * 4 + r;
        float v = acc[mt][nt][r] + bv;
        if (MODE == 2) {
          v += res[(size_t)m * D_DIM + n];
          Cf[(size_t)m * D_DIM + n] = v;
        } else if (MODE == 0) {
          Cb[(size_t)(bn >> 10) * MD + (size_t)m * D_DIM + (n & 1023)] = (bf16_t)v;
        } else {  // MODE 3
          Cb[(size_t)(bm >> 10) * D_DIM * D_DIM + (size_t)(m & 1023) * D_DIM + n] =
              (bf16_t)v;
        }
      }
    }
  }
}

// ---------------------------------------------------------------------------
// Prelude: z<4  -> weight transpose+cast (Wt[n][k] = (bf16)W[k][n]);
//          z in [4,22) -> flat fp32->bf16 cast of x | Wk | Wq;
//          z==22 -> fused bias (K-split GEMV), folded in to save a dispatch.
// ---------------------------------------------------------------------------
__global__ __launch_bounds__(256) void prep_all(
    const float* __restrict__ s0, const float* __restrict__ s1,
    const float* __restrict__ s2, const float* __restrict__ s3,
    bf16_t* __restrict__ d0, bf16_t* __restrict__ d1,
    bf16_t* __restrict__ d2, bf16_t* __restrict__ d3,
    const float* __restrict__ x, const float* __restrict__ Wk,
    const float* __restrict__ Wq, bf16_t* __restrict__ xb,
    bf16_t* __restrict__ wkb, bf16_t* __restrict__ wqb,
    const float* __restrict__ bv, const float* __restrict__ bk,
    const float* __restrict__ bkp, const float* __restrict__ bq,
    const float* __restrict__ bqp, float* __restrict__ fb) {
  const int z = blockIdx.z;
  if (z == 22) {
    // fused bias: fb[c]=bv[c]; fb[1024+c]=bk@Wkp[:,c]+bkp[c]; fb[2048+c] q.
    // grid slice: x<16 (column tiles of 64), y<3 (t). 4 K-partitions x 64 cols.
    if (blockIdx.x >= 16 || blockIdx.y >= 3) return;
    const int t = blockIdx.y;
    const int cb = blockIdx.x * 64;
    const int c = threadIdx.x & 63;
    const int p = threadIdx.x >> 6;
    if (t == 0) {
      if (p == 0) fb[cb + c] = bv[cb + c];
      return;
    }
    const float* W = (t == 1) ? s1 : s2;   // Wkp : Wqp (fp32 originals)
    const float* b1 = (t == 1) ? bk : bq;
    const float* b2 = (t == 1) ? bkp : bqp;
    const int k0 = p * 256;
    float s = 0.f;
#pragma unroll 8
    for (int k = 0; k < 256; k++)
      s = fmaf(b1[k0 + k], W[(size_t)(k0 + k) * D_DIM + cb + c], s);
    __shared__ float red[4][64];
    red[p][c] = s;
    __syncthreads();
    if (p == 0)
      fb[t * 1024 + cb + c] =
          red[0][c] + red[1][c] + red[2][c] + red[3][c] + b2[cb + c];
  } else if (z < 4) {
    const float* srcs[4] = {s0, s1, s2, s3};
    bf16_t* dsts[4] = {d0, d1, d2, d3};
    const float* W = srcs[z];
    bf16_t* Wt = dsts[z];
    __shared__ float tile[32][33];
    const int bx = blockIdx.x * 32;  // n
    const int by = blockIdx.y * 32;  // k
    const int tx = threadIdx.x & 31, ty = threadIdx.x >> 5;  // 32 x 8
#pragma unroll
    for (int r = 0; r < 32; r += 8)
      tile[ty + r][tx] = W[(size_t)(by + ty + r) * D_DIM + bx + tx];
    __syncthreads();
#pragma unroll
    for (int r = 0; r < 32; r += 8)
      Wt[(size_t)(bx + ty + r) * D_DIM + by + tx] = (bf16_t)tile[tx][ty + r];
  } else {
    // 18 z-slices x 1024 blocks x 256 thr = 4718592 float4 groups exactly
    size_t i = ((size_t)(z - 4) * 1024 + blockIdx.y * 32 + blockIdx.x) * 256 +
               threadIdx.x;
    const float* src;
    bf16_t* dst;
    size_t off;
    if (i < 4194304) { src = x; dst = xb; off = i; }
    else if (i < 4456448) { src = Wk; dst = wkb; off = i - 4194304; }
    else { src = Wq; dst = wqb; off = i - 4456448; }
    const float4 v = ((const float4*)src)[off];
    bf16x4 o;
    o[0] = (bf16_t)v.x; o[1] = (bf16_t)v.y; o[2] = (bf16_t)v.z; o[3] = (bf16_t)v.w;
    ((bf16x4*)dst)[off] = o;
  }
}

// ---------------------------------------------------------------------------
// Fused phasor scan + LayerNorm. Block = (chunk, b), 512 threads, 64 KB LDS.
// Trig via native __sincosf (phases O(1); error ~1e-6 << bf16 rounding).
// Tail: block (0,0) also reduces the 128 ortho partials (ready by stream
// order) -> saves the ortho_final dispatch.
// ---------------------------------------------------------------------------
__global__ __launch_bounds__(512) void scan_ln(const bf16_t* __restrict__ vb,
                                               const bf16_t* __restrict__ kp,
                                               const bf16_t* __restrict__ qp,
                                               const float* __restrict__ g,
                                               const float* __restrict__ bl,
                                               bf16_t* __restrict__ outb,
                                               const float* __restrict__ partial,
                                               float* __restrict__ orthop) {
  __shared__ bf16_t retl[32 * 1024];   // 64 KB
  __shared__ float osum[8];
  const int chunk = blockIdx.x;
  const int b = blockIdx.y;
  const int tid = threadIdx.x;
  const int lane = tid & 63, wave = tid >> 6;
  const int c = tid * 2;
  const size_t base = ((size_t)(b * S_DIM + chunk * CHUNK)) * D_DIM + c;
  float2 mr = {0.f, 0.f}, mi = {0.f, 0.f};
  const float inv = 0.015625f;  // 1/sqrt(4096)

  for (int half = 0; half < 2; half++) {
#pragma unroll 4
    for (int s8 = 0; s8 < 32; s8++) {
      const int s = half * 32 + s8;
      const size_t off = base + (size_t)s * D_DIM;
      bf16x2 v2 = *(const bf16x2*)(vb + off);
      bf16x2 k2 = *(const bf16x2*)(kp + off);
      bf16x2 q2 = *(const bf16x2*)(qp + off);
      float sk, ck, sq, cq;
      __sincosf((float)k2[0], &sk, &ck);
      mr.x = fmaf((float)v2[0], ck, mr.x);
      mi.x = fmaf((float)v2[0], sk, mi.x);
      __sincosf((float)k2[1], &sk, &ck);
      mr.y = fmaf((float)v2[1], ck, mr.y);
      mi.y = fmaf((float)v2[1], sk, mi.y);
      bf16x2 r;
      __sincosf((float)q2[0], &sq, &cq);
      r[0] = (bf16_t)((mr.x * cq + mi.x * sq) * inv);
      __sincosf((float)q2[1], &sq, &cq);
      r[1] = (bf16_t)((mr.y * cq + mi.y * sq) * inv);
      *(bf16x2*)(retl + s8 * 1024 + c) = r;
    }
    __syncthreads();
#pragma unroll
    for (int j = 0; j < 4; j++) {
      const int r8 = wave * 4 + j;
      const int col0 = lane * 16;
      const bf16x8 va = *(const bf16x8*)(retl + r8 * 1024 + col0);
      const bf16x8 vb8 = *(const bf16x8*)(retl + r8 * 1024 + col0 + 8);
      float vf[16];
#pragma unroll
      for (int k = 0; k < 8; k++) { vf[k] = (float)va[k]; vf[8 + k] = (float)vb8[k]; }
      float s = 0.f, ss = 0.f;
#pragma unroll
      for (int k = 0; k < 16; k++) { s += vf[k]; ss += vf[k] * vf[k]; }
#pragma unroll
      for (int o = 32; o > 0; o >>= 1) {
        s += __shfl_down(s, o);
        ss += __shfl_down(ss, o);
      }
      s = __shfl(s, 0);
      ss = __shfl(ss, 0);
      const float mu = s * (1.f / D_DIM);
      const float var = ss * (1.f / D_DIM) - mu * mu;
      const float rs = 1.f / sqrtf(var + 1e-5f);
      const int m = b * S_DIM + chunk * CHUNK + half * 32 + r8;
      bf16x8 o1, o2;
#pragma unroll
      for (int q = 0; q < 4; q++) {
        const float4 gv = *(const float4*)(g + col0 + 4 * q);
        const float4 bv = *(const float4*)(bl + col0 + 4 * q);
        const int kbase = 4 * q;
        float r0 = (vf[kbase + 0] - mu) * rs * gv.x + bv.x;
        float r1 = (vf[kbase + 1] - mu) * rs * gv.y + bv.y;
        float r2 = (vf[kbase + 2] - mu) * rs * gv.z + bv.z;
        float r3 = (vf[kbase + 3] - mu) * rs * gv.w + bv.w;
        if (q < 2) {
          o1[kbase + 0] = (bf16_t)r0; o1[kbase + 1] = (bf16_t)r1;
          o1[kbase + 2] = (bf16_t)r2; o1[kbase + 3] = (bf16_t)r3;
        } else {
          o2[kbase - 8] = (bf16_t)r0; o2[kbase - 7] = (bf16_t)r1;
          o2[kbase - 6] = (bf16_t)r2; o2[kbase - 5] = (bf16_t)r3;
        }
      }
      *(bf16x8*)(outb + (size_t)m * D_DIM + col0) = o1;
      *(bf16x8*)(outb + (size_t)m * D_DIM + col0 + 8) = o2;
    }
    __syncthreads();
  }

  // ---- ortho finalize (block (0,0) only; partial[] ready by stream order) --
  if (blockIdx.x == 0 && blockIdx.y == 0) {
    float s = (tid < 128) ? partial[tid] : 0.f;
#pragma unroll
    for (int o = 32; o > 0; o >>= 1) s += __shfl_down(s, o);
    if (lane == 0) osum[wave] = s;
    __syncthreads();
    if (tid == 0) {
      double tot = (double)osum[0] + osum[1];  // waves 2+ contributed zeros
      const double denom = (double)(32 * 31) * 1024.0 + 1e-6;
      orthop[0] = (float)(tot / denom);
    }
  }
}

// ---------------------------------------------------------------------------
// Ortho loss from bf16 kphase: cos(kp_i)cos(kp_j)+sin..sin.. = cos(kp_i-kp_j)
// ---------------------------------------------------------------------------
__global__ __launch_bounds__(256) void ortho_partial(const bf16_t* __restrict__ kp,
                                                     const int* __restrict__ idx,
                                                     float* __restrict__ partial) {
  const int i = blockIdx.x;  // 0..31
  const int b = blockIdx.y;  // 0..3
  const int ri = idx[i];
  const bf16x4 ab = *(const bf16x4*)(kp + ((size_t)b * S_DIM + ri) * D_DIM + threadIdx.x * 4);
  float a0 = (float)ab[0], a1 = (float)ab[1], a2 = (float)ab[2], a3 = (float)ab[3];
  float sum = 0.f;
  for (int j = 0; j < 32; j++) {
    if (j == i) continue;
    const int rj = idx[j];
    const bf16x4 cb = *(const bf16x4*)(kp + ((size_t)b * S_DIM + rj) * D_DIM + threadIdx.x * 4);
    float d0 = __cosf(a0 - (float)cb[0]);
    float d1 = __cosf(a1 - (float)cb[1]);
    float d2 = __cosf(a2 - (float)cb[2]);
    float d3 = __cosf(a3 - (float)cb[3]);
    sum += d0 * d0 + d1 * d1 + d2 * d2 + d3 * d3;
  }
#pragma unroll
  for (int o = 32; o > 0; o >>= 1) sum += __shfl_down(sum, o);
  __shared__ float red[4];
  if ((threadIdx.x & 63) == 0) red[threadIdx.x >> 6] = sum;
  __syncthreads();
  if (threadIdx.x == 0) partial[b * 32 + i] = red[0] + red[1] + red[2] + red[3];
}

// ---------------------------------------------------------------------------
// Orchestration (6 dispatches). ws layout (MB offsets; peak 160 MB):
//   [  0,  6) QKVT bf16 [3072,1024] = [WvT | WkkpT | WqqpT]
//   [  6,  8) WoT            [  8, 12) WkpT||WqpT [2048,1024]
//   [ 12,  +) fused bias (3072 f32) + partial (128 f32)
//   [ 13, 17) Wk_b||Wq_b (dead after wfuse GEMM)
//   [ 32, 64) xb             -> lnb after mega GEMM
//   [ 64, 96) value_b        [ 96,128) kp_b        [128,160) qp_b
// ---------------------------------------------------------------------------
extern "C" void kernel_launch(void* const* d_in, const int* in_sizes, int n_in,
                              void* d_out, int out_size, void* d_ws, size_t ws_size,
                              hipStream_t stream) {
  const float* x = (const float*)d_in[0];
  const float* Wk = (const float*)d_in[1];
  const float* bk = (const float*)d_in[2];
  const float* Wv = (const float*)d_in[3];
  const float* bv = (const float*)d_in[4];
  const float* Wq = (const float*)d_in[5];
  const float* bq = (const float*)d_in[6];
  const float* Wkp = (const float*)d_in[7];
  const float* bkp = (const float*)d_in[8];
  const float* Wqp = (const float*)d_in[9];
  const float* bqp = (const float*)d_in[10];
  const float* ln_g = (const float*)d_in[11];
  const float* ln_b = (const float*)d_in[12];
  const float* Wo = (const float*)d_in[13];
  const float* bo = (const float*)d_in[14];
  const int* idx = (const int*)d_in[15];

  float* out = (float*)d_out;
  float* ortho_out = out + MD;

  char* ws = (char*)d_ws;
  const size_t MB = 1024 * 1024;
  bf16_t* QKVT = (bf16_t*)(ws + 0 * MB);     // [3072,1024]
  bf16_t* WoT = (bf16_t*)(ws + 6 * MB);
  bf16_t* WkpT2 = (bf16_t*)(ws + 8 * MB);    // [2048,1024]
  float* fbias = (float*)(ws + 12 * MB);     // 3072
  float* partial = (float*)(ws + 12 * MB + 16 * 1024);  // 128
  bf16_t* Wkqb = (bf16_t*)(ws + 13 * MB);    // Wk_b || Wq_b  [2][1024][1024]
  bf16_t* xb = (bf16_t*)(ws + 32 * MB);
  bf16_t* mega_out = (bf16_t*)(ws + 64 * MB);  // [3][16384][1024]
  bf16_t* kp_b = mega_out + MD;
  bf16_t* qp_b = mega_out + 2 * MD;
  bf16_t* lnb = (bf16_t*)(ws + 32 * MB);     // reuses xb (dead after mega)

  // 0. prelude: transposes + casts + fused bias (one dispatch), wfuse GEMM
  prep_all<<<dim3(32, 32, 23), 256, 0, stream>>>(
      Wv, Wkp, Wqp, Wo, QKVT, WkpT2, WkpT2 + (size_t)D_DIM * D_DIM, WoT,
      x, Wk, Wq, xb, Wkqb, Wkqb + (size_t)D_DIM * D_DIM,
      bv, bk, bkp, bq, bqp, fbias);
  // WkkpT/WqqpT = (WkpT||WqpT) @ (Wk_b||Wq_b)^T  -> QKVT rows [1024,3072)
  gemm_mfma<3><<<128, 256, 0, stream>>>(WkpT2, Wkqb, nullptr, nullptr, nullptr,
                                        QKVT + (size_t)D_DIM * D_DIM);

  // 1. mega GEMM (4-fused-phase 256^2): [value|kp|qp] = xb @ QKVT^T + fbias
  gemm256<0><<<768, 512, 0, stream>>>(xb, QKVT, fbias, nullptr, nullptr,
                                      mega_out);
  // 2. ortho from kp_b
  ortho_partial<<<dim3(32, B_DIM), 256, 0, stream>>>(kp_b, idx, partial);
  // 3. fused trig + chunk cumsum + retrieve + LayerNorm -> lnb (xb dead);
  //    block (0,0) also finalizes ortho scalar.
  scan_ln<<<dim3(NC, B_DIM), 512, 0, stream>>>(mega_out, kp_b, qp_b, ln_g, ln_b,
                                               lnb, partial, ortho_out);
  // 4. out = x + lnb@Wo + bo  (4-fused-phase 256^2)
  gemm256<2><<<256, 512, 0, stream>>>(lnb, WoT, bo, x, out, nullptr);
}